// Round 8
// baseline (366.469 us; speedup 1.0000x reference)
//
#include <hip/hip_runtime.h>

#define N_B   262144
#define BM    128      // rows per block, 256 threads = 4 waves (2 fw x 2 rw)
#define LDA   264      // hA row stride in halves (528 B)

typedef _Float16 f16x8  __attribute__((ext_vector_type(8)));
typedef _Float16 f16x4  __attribute__((ext_vector_type(4)));
typedef float    f32x4  __attribute__((ext_vector_type(4)));

// ---------------------------------------------------------------------------
// Precompute (68 blocks):
//  blocks 0..63 : Mt[l][n][k] (l=b>>4, 16 rows each), K=256 circulant over the
//                 rotated state t=[h0..h252,x0,x1,x2], lw folded at k==n (n<=252).
//  blocks 64..67: W1t[n][k] = W1[k][n].
// ---------------------------------------------------------------------------
__global__ void fno_precompute(const float* __restrict__ W1,
                               const float* __restrict__ fw,
                               const float* __restrict__ lw,
                               _Float16* __restrict__ Mt,    // [4][256][256]
                               _Float16* __restrict__ W1t)   // [256][64]
{
    const int t = threadIdx.x;          // 0..255
    const int b = blockIdx.x;
    if (b < 64) {
        const int l  = b >> 4;
        const int ng = b & 15;
        __shared__ float cosTab[256];
        __shared__ float cs[256];
        cosTab[t] = cosf((float)t * (6.28318530717958647692f / 256.0f));
        __syncthreads();
        {
            const float* fwl = fw + l * 129;
            float s = fwl[0];
            #pragma unroll 4
            for (int k = 1; k < 128; ++k)
                s += 2.0f * fwl[k] * cosTab[(k * t) & 255];
            s += fwl[128] * ((t & 1) ? -1.0f : 1.0f);
            cs[t] = s * (1.0f / 256.0f);
        }
        __syncthreads();
        for (int idx = t; idx < 16 * 256; idx += 256) {
            const int n = ng * 16 + (idx >> 8);
            const int k = idx & 255;
            float v;
            if (k < 253) {
                v = cs[(n - k - 3) & 255];        // coeff of t[k]=h[k] (d[k+3])
                if (k == n) v += lw[l * 256 + n]; // aligned lw diagonal (n<=252)
            } else {
                v = cs[(n - (k - 253)) & 255];    // coeff of t[253+m]=x[m]
            }
            Mt[((size_t)l * 256 + n) * 256 + k] = (_Float16)v;
        }
    } else {
        const int base = (b - 64) * 4096;
        #pragma unroll
        for (int i = 0; i < 16; ++i) {
            const int idx = base + t + i * 256;
            const int n = idx >> 6, k = idx & 63;
            W1t[idx] = (_Float16)W1[k * 256 + n];
        }
    }
}

// ---------------------------------------------------------------------------
// Fused main kernel, 16x16x32 MFMA, K=256 rotated state.
// Block = 128 rows x 256 threads (4 waves): fw = wid&1 -> features
// [128fw,128fw+128) (8 ft-tiles); rw = wid>>1 -> rows [64rw,64rw+64) (4 rt).
// Per K-step (32): 8 mfrag (L2) + 4 hfrag (LDS) + 32 MFMA  -> only 8 steps
// per layer: minimal load stream per MFMA-cycle (latency-stall reduction).
// mfma(mfrag, hfrag): D lane = h-row (lane&15), regs = 4 consecutive features.
// State: hA cols 0..252 = h, 253..255 = x (persistent), 256..258 = h tail
// (f16, lw-chained in epilogue).
// ---------------------------------------------------------------------------
__global__ __launch_bounds__(256, 2)
void fno_main(const float* __restrict__ mu,
              const float* __restrict__ x,
              const float* __restrict__ b1,
              const float* __restrict__ W2,
              const float* __restrict__ b2,
              const float* __restrict__ lw,
              const _Float16* __restrict__ Mt,
              const _Float16* __restrict__ W1t,
              float* __restrict__ out)
{
    __shared__ __align__(16) _Float16 hA[BM * LDA];   // 67,584 B
    __shared__ float b1s[256];                        // bias; reused as decoder red
    __shared__ float W2s[256];

    const int t    = threadIdx.x;
    const int wid  = t >> 6;
    const int fws  = wid & 1;       // feature stripe 128*fws
    const int rw   = wid >> 1;      // row half 64*rw
    const int lane = t & 63;
    const int i16  = lane & 15;     // mfrag feature / hfrag row / D h-row
    const int q    = lane >> 4;     // k-chunk 8q (inputs) / feature group 4q (D)
    const int r0   = blockIdx.x * BM;

    // ---- stage mu -> hA cols 0..63 ; x -> cols 253..255 ----
    {
        const float4* mu4 = (const float4*)mu + (size_t)r0 * 16;  // 16 float4/row
        #pragma unroll
        for (int j = 0; j < 8; ++j) {
            int f = t + 256 * j;              // [0, 2048)
            int row = f >> 4, c4 = f & 15;
            float4 v = mu4[f];
            f16x4 h;
            h[0] = (_Float16)v.x; h[1] = (_Float16)v.y;
            h[2] = (_Float16)v.z; h[3] = (_Float16)v.w;
            *(f16x4*)&hA[row * LDA + c4 * 4] = h;
        }
    }
    if (t < BM) {
        const float* xp = x + (size_t)(r0 + t) * 3;
        hA[t * LDA + 253] = (_Float16)xp[0];
        hA[t * LDA + 254] = (_Float16)xp[1];
        hA[t * LDA + 255] = (_Float16)xp[2];
    }
    b1s[t] = b1[t];
    W2s[t] = (t >= 253) ? 0.f : W2[t];
    __syncthreads();

    f32x4 acc[8][4];   // [feature-tile][row-tile], 128 AGPRs

    // ================= encoder: h = relu(mu @ W1 + b1), K = 64 =================
    #pragma unroll
    for (int ft = 0; ft < 8; ++ft)
        #pragma unroll
        for (int rt = 0; rt < 4; ++rt)
            acc[ft][rt] = (f32x4){0.f, 0.f, 0.f, 0.f};

    #pragma unroll
    for (int ks = 0; ks < 2; ++ks) {
        const int kb = 32 * ks;
        f16x8 mfrag[8];
        #pragma unroll
        for (int ft = 0; ft < 8; ++ft) {
            int n = 128 * fws + 16 * ft + i16;
            mfrag[ft] = *(const f16x8*)(W1t + n * 64 + kb + 8 * q);
        }
        #pragma unroll
        for (int rt = 0; rt < 4; ++rt) {
            f16x8 hfrag = *(const f16x8*)&hA[(64 * rw + 16 * rt + i16) * LDA + kb + 8 * q];
            #pragma unroll
            for (int ft = 0; ft < 8; ++ft)
                acc[ft][rt] = __builtin_amdgcn_mfma_f32_16x16x32_f16(
                    mfrag[ft], hfrag, acc[ft][rt], 0, 0, 0);
        }
    }
    __syncthreads();   // all reads of mu-region done before overwrite
    #pragma unroll
    for (int ft = 0; ft < 8; ++ft) {
        const int f0 = 128 * fws + 16 * ft + 4 * q;
        const float4 bias = *(const float4*)&b1s[f0];
        #pragma unroll
        for (int rt = 0; rt < 4; ++rt) {
            const int row = 64 * rw + 16 * rt + i16;
            float v0 = fmaxf(acc[ft][rt][0] + bias.x, 0.f);
            float v1 = fmaxf(acc[ft][rt][1] + bias.y, 0.f);
            float v2 = fmaxf(acc[ft][rt][2] + bias.z, 0.f);
            float v3 = fmaxf(acc[ft][rt][3] + bias.w, 0.f);
            if (fws == 1 && ft == 7 && q == 3) {
                // features 252..255: col 252 = h252; tails h253..255 -> 256..258
                hA[row * LDA + 252] = (_Float16)v0;
                hA[row * LDA + 256] = (_Float16)v1;
                hA[row * LDA + 257] = (_Float16)v2;
                hA[row * LDA + 258] = (_Float16)v3;
            } else {
                f16x4 hv;
                hv[0] = (_Float16)v0; hv[1] = (_Float16)v1;
                hv[2] = (_Float16)v2; hv[3] = (_Float16)v3;
                *(f16x4*)&hA[row * LDA + f0] = hv;
            }
        }
    }

    // ================= 4 Fourier layers =================
    #pragma unroll 1
    for (int l = 0; l < 4; ++l) {
        __syncthreads();   // state writes visible
        #pragma unroll
        for (int ft = 0; ft < 8; ++ft)
            #pragma unroll
            for (int rt = 0; rt < 4; ++rt)
                acc[ft][rt] = (f32x4){0.f, 0.f, 0.f, 0.f};

        const _Float16* Ml = Mt + (size_t)l * 65536
                           + (size_t)(128 * fws + i16) * 256 + 8 * q;
        const float lw253 = lw[l * 256 + 253];
        const float lw254 = lw[l * 256 + 254];
        const float lw255 = lw[l * 256 + 255];

        #pragma unroll
        for (int ks = 0; ks < 8; ++ks) {
            const int kb = 32 * ks;
            f16x8 mfrag[8];
            #pragma unroll
            for (int ft = 0; ft < 8; ++ft)
                mfrag[ft] = *(const f16x8*)(Ml + 16 * 256 * ft + kb);
            #pragma unroll
            for (int rt = 0; rt < 4; ++rt) {
                f16x8 hfrag = *(const f16x8*)&hA[(64 * rw + 16 * rt + i16) * LDA + kb + 8 * q];
                #pragma unroll
                for (int ft = 0; ft < 8; ++ft)
                    acc[ft][rt] = __builtin_amdgcn_mfma_f32_16x16x32_f16(
                        mfrag[ft], hfrag, acc[ft][rt], 0, 0, 0);
            }
        }
        __syncthreads();   // all state reads done before overwrite
        #pragma unroll
        for (int ft = 0; ft < 8; ++ft) {
            const int f0 = 128 * fws + 16 * ft + 4 * q;
            #pragma unroll
            for (int rt = 0; rt < 4; ++rt) {
                const int row = 64 * rw + 16 * rt + i16;
                if (fws == 1 && ft == 7 && q == 3) {
                    // tails: lw not folded in Mt for n=253..255; chain via f16
                    float p0 = (float)hA[row * LDA + 256];
                    float p1 = (float)hA[row * LDA + 257];
                    float p2 = (float)hA[row * LDA + 258];
                    hA[row * LDA + 252] = (_Float16)fmaxf(acc[ft][rt][0], 0.f);
                    hA[row * LDA + 256] = (_Float16)fmaxf(acc[ft][rt][1] + lw253 * p0, 0.f);
                    hA[row * LDA + 257] = (_Float16)fmaxf(acc[ft][rt][2] + lw254 * p1, 0.f);
                    hA[row * LDA + 258] = (_Float16)fmaxf(acc[ft][rt][3] + lw255 * p2, 0.f);
                } else {
                    f16x4 hv;
                    hv[0] = (_Float16)fmaxf(acc[ft][rt][0], 0.f);
                    hv[1] = (_Float16)fmaxf(acc[ft][rt][1], 0.f);
                    hv[2] = (_Float16)fmaxf(acc[ft][rt][2], 0.f);
                    hv[3] = (_Float16)fmaxf(acc[ft][rt][3], 0.f);
                    *(f16x4*)&hA[row * LDA + f0] = hv;
                }
            }
        }
    }

    // ================= decoder: out = h @ W2 + b2 =============================
    __syncthreads();
    {
        float* redS = b1s;                 // b1s dead since encoder epilogue
        const int r  = t & 127;
        const int hf = t >> 7;             // two threads per row
        const int n0 = hf * 128;
        float s = 0.f;
        #pragma unroll
        for (int j = 0; j < 16; ++j) {
            f16x8 v = *(const f16x8*)&hA[r * LDA + n0 + 8 * j];
            const float* wp = &W2s[n0 + 8 * j];
            s += (float)v[0] * wp[0] + (float)v[1] * wp[1]
               + (float)v[2] * wp[2] + (float)v[3] * wp[3]
               + (float)v[4] * wp[4] + (float)v[5] * wp[5]
               + (float)v[6] * wp[6] + (float)v[7] * wp[7];
        }
        if (hf == 0)
            s += (float)hA[r * LDA + 256] * W2[253]
               + (float)hA[r * LDA + 257] * W2[254]
               + (float)hA[r * LDA + 258] * W2[255];
        redS[t] = s;
        __syncthreads();
        if (t < BM)
            out[r0 + t] = redS[t] + redS[128 + t] + b2[0];
    }
}

// ---------------------------------------------------------------------------
extern "C" void kernel_launch(void* const* d_in, const int* in_sizes, int n_in,
                              void* d_out, int out_size, void* d_ws, size_t ws_size,
                              hipStream_t stream) {
    const float* mu = (const float*)d_in[0];
    const float* x  = (const float*)d_in[1];
    const float* W1 = (const float*)d_in[2];
    const float* b1 = (const float*)d_in[3];
    const float* fw = (const float*)d_in[4];
    const float* lw = (const float*)d_in[5];
    const float* W2 = (const float*)d_in[6];
    const float* b2 = (const float*)d_in[7];
    float* out = (float*)d_out;

    // workspace: Mt [4][256][256] f16 (524,288 B) + W1t [256][64] f16 (32 KB)
    _Float16* Mt  = (_Float16*)d_ws;
    _Float16* W1t = Mt + 4 * 256 * 256;

    fno_precompute<<<68, 256, 0, stream>>>(W1, fw, lw, Mt, W1t);
    fno_main<<<N_B / BM, 256, 0, stream>>>(mu, x, b1, W2, b2, lw, Mt, W1t, out);
}